// Round 19
// baseline (99.989 us; speedup 1.0000x reference)
//
#include <hip/hip_runtime.h>
#include <math.h>

// A=32, B=16, C=16, D=16, KK=9, KKA=288, BSZ=4, L=196, BL=784
// po[b_,d] = sum_t G'_d[t,b_] * x[t,b_,d],  G'_d = (H_d + I) @ coeff
//   H_d[t,n] = h_d[(n-t) mod 288] (row-invariant circulant)
//   x = gelu(pu @ mpose_w_d^T + mb_d) via MFMA, same C/D layout as G'.

typedef __attribute__((ext_vector_type(8))) short bf16x8;
typedef __attribute__((ext_vector_type(4))) float f32x4;

__device__ inline float4 ld4(const float* p) { return *reinterpret_cast<const float4*>(p); }
__device__ inline void st4(float* p, float4 v) { *reinterpret_cast<float4*>(p) = v; }
__device__ inline unsigned short f2bf(float f) {
  union { float f; unsigned int i; } v; v.f = f;
  unsigned int r = v.i + 0x7FFFu + ((v.i >> 16) & 1u);
  return (unsigned short)(r >> 16);
}
// exact-gelu via A&S 7.1.26 erf approx, |err_erf| < 1.5e-7
__device__ inline float gelu_f(float v) {
  float u = v * 0.70710678118654752f;
  float au = fabsf(u);
  float t = __builtin_amdgcn_rcpf(fmaf(0.3275911f, au, 1.f));
  float poly = t * fmaf(t, fmaf(t, fmaf(t, fmaf(t, 1.061405429f, -1.453152027f),
                                        1.421413741f), -0.284496736f),
                        0.254829592f);
  float e = __expf(-u * u);
  float r = fmaf(-poly, e, 1.f);
  float erfv = copysignf(r, u);
  return 0.5f * v * (1.f + erfv);
}

// ---------------------------------------------------------------------------
// Kernel TR: NHWC transpose only. grid(4,17): pose -> poseT, ch=16 -> aT.
// ---------------------------------------------------------------------------
__global__ __launch_bounds__(256) void k_tr(const float* __restrict__ pose,
                                            const float* __restrict__ a_img,
                                            float* __restrict__ poseT,
                                            float* __restrict__ aT) {
  __shared__ float s[32 * 201];
  int b = blockIdx.x, ch = blockIdx.y, tid = threadIdx.x;
  const float* src = (ch < 16) ? (pose + (b * 512 + ch * 32) * 196)
                               : (a_img + b * 32 * 196);
  for (int e = tid; e < 6272; e += 256) {
    int c = e / 196, l = e - c * 196;
    s[c * 201 + l] = src[e];
  }
  __syncthreads();
  if (ch < 16) {
    float* dst = poseT + b * 196 * 512 + ch * 32;
    for (int e = tid; e < 6272; e += 256) {
      int l = e >> 5, c = e & 31;
      dst[l * 512 + c] = s[c * 201 + l];
    }
  } else {
    float* dst = aT + b * 196 * 32;
    for (int e = tid; e < 6272; e += 256) {
      int l = e >> 5, c = e & 31;
      dst[l * 32 + c] = s[c * 201 + l];
    }
  }
}

// ---------------------------------------------------------------------------
// Kernel 1 (merged): bids 0..95 = htab (d=bid/6, chunk=bid%6), LDS aliased
// into s_pu; bids 96..991 = rowprep, sixteen-group decode so group s runs on
// XCD s%8, matching gterm's reader (rg = xcd + 8*k7).
// ws_H: [d][mt 18][kk 9][lane 64][j 8]; t=mt*16+(l&15), n=kk*32+(l>>4)*8+j.
// ---------------------------------------------------------------------------
__global__ __launch_bounds__(256) void k_rowprep(
    const float* __restrict__ cw,
    const float* __restrict__ poseT, const float* __restrict__ aT,
    const float* __restrict__ cpose2_w, const float* __restrict__ cpose2_b,
    const float* __restrict__ ln_g, const float* __restrict__ ln_b,
    const float* __restrict__ sp_w, const float* __restrict__ sp_b,
    float* __restrict__ out_a, unsigned short* __restrict__ ws_pu,
    unsigned short* __restrict__ ws_cb, unsigned short* __restrict__ ws_H) {
  __shared__ __align__(16) float s_pu[288 * 20];   // aliased: s_l2 / htab tables
#define s_l2 s_pu
  __shared__ __align__(16) float s_lg[288 * 20];
  __shared__ float s_au[288];
  __shared__ float s_mu[144], s_rs[144];
  __shared__ float s_ga[32], s_be[32];
  __shared__ float s_part[256], s_pau[16];
  __shared__ float s_as[16];

  int bid = blockIdx.x, tid = threadIdx.x;

  if (bid < 96) {
    // ---- htab branch (LDS overlaid on s_pu) ----
    float* s_h2 = s_pu;             // 576
    float* s_cs = s_pu + 576;       // 288
    float* s_sn = s_pu + 864;       // 288
    float* s_wr = s_pu + 1152;      // 145
    float* s_wi = s_pu + 1297;      // 145
    int d = bid / 6, chunk = bid % 6;
    for (int m = tid; m < 288; m += 256) {
      float sn, cs;
      sincosf((float)m * (6.283185307179586f / 288.f), &sn, &cs);
      s_cs[m] = cs; s_sn[m] = sn;
    }
    for (int f = tid; f < 145; f += 256) {
      s_wr[f] = cw[(f * 16 + d) * 2 + 0];
      s_wi[f] = cw[(f * 16 + d) * 2 + 1];
    }
    __syncthreads();
    for (int t = tid; t < 288; t += 256) {
      float acc = s_wr[0] + ((t & 1) ? -s_wr[144] : s_wr[144]);
      for (int f = 1; f < 144; ++f) {
        int m = (f * t) % 288;
        acc = fmaf(2.f * s_wr[f], s_cs[m], acc);
        acc = fmaf(-2.f * s_wi[f], s_sn[m], acc);
      }
      float h = acc * (1.f / 288.f);
      s_h2[t] = h;
      s_h2[t + 288] = h;
    }
    __syncthreads();
    for (int e = tid; e < 13824; e += 256) {
      int j = e & 7, l = (e >> 3) & 63;
      int kk = (e >> 9) % 9, mtl = (e >> 9) / 9;
      int mt = chunk * 3 + mtl;
      int m = l & 15, g = l >> 4;
      int n = kk * 32 + g * 8 + j, t = mt * 16 + m;
      float v = s_h2[n - t + 288] + ((n == t) ? 1.f : 0.f);
      ws_H[d * 82944 + ((mt * 9 + kk) * 64 + l) * 8 + j] = f2bf(v);
    }
    return;
  }

  // ---- rowprep branch: sixteen-group decode ----
  int rb = bid - 96;
  int x = rb & 7, jj0 = rb >> 3;          // jj0 in [0,112)
  int s16 = x + 8 * (jj0 % 7);            // [0,56)
  if (s16 >= 49) return;
  int row = s16 * 16 + (jj0 / 7);

  int b = row / 196, loc = row % 196, i0 = loc / 14, j0 = loc % 14;
  int b_ = tid & 15;

  if (tid < 32) { s_ga[tid] = ln_g[tid]; s_be[tid] = ln_b[tid]; }

  float wcol[16];
#pragma unroll
  for (int q = 0; q < 4; ++q) {
    float4 v = ld4(&cpose2_w[b_ * 16 + 4 * q]);
    wcol[4 * q] = v.x; wcol[4 * q + 1] = v.y;
    wcol[4 * q + 2] = v.z; wcol[4 * q + 3] = v.w;
  }
  float cbv = cpose2_b[b_];

  const float* pT = poseT + b * 196 * 512;
  for (int e = tid; e < 1152; e += 256) {
    int q = e & 3, n = e >> 2;
    int kk = n >> 5, a = n & 31;
    int ki = (kk * 11) >> 5, kj = kk - 3 * ki;
    int yy = i0 + ki - 1, xx = j0 + kj - 1;
    float4 v = make_float4(0.f, 0.f, 0.f, 0.f);
    if ((unsigned)yy < 14u && (unsigned)xx < 14u)
      v = ld4(&pT[(yy * 14 + xx) * 512 + a * 16 + q * 4]);
    st4(&s_pu[n * 20 + q * 4], v);
  }
  const float* aTb = aT + b * 196 * 32;
  for (int n = tid; n < 288; n += 256) {
    int kk = n >> 5, a = n & 31;
    int ki = (kk * 11) >> 5, kj = kk - 3 * ki;
    int yy = i0 + ki - 1, xx = j0 + kj - 1;
    float v = 0.f;
    if ((unsigned)yy < 14u && (unsigned)xx < 14u)
      v = aTb[(yy * 14 + xx) * 32 + a];
    s_au[n] = v;
  }
  __syncthreads();

  // pu compact A-frags (EARLY — s_pu dead after logit pass)
  for (int e = tid; e < 4608; e += 256) {
    int jj = e & 7, l2 = (e >> 3) & 31, mt = e >> 8;
    int m = l2 & 15, c = (l2 >> 4) * 8 + jj;
    ws_pu[row * 4608 + e] = f2bf(s_pu[(mt * 16 + m) * 20 + c]);
  }

  // logit[n,b_]
  {
    int n0 = tid >> 4;
#pragma unroll 3
    for (int k = 0; k < 18; ++k) {
      int n = n0 + 16 * k;
      const float* pr = &s_pu[n * 20];
      float acc = cbv;
#pragma unroll
      for (int q = 0; q < 4; ++q) {
        float4 p = ld4(pr + 4 * q);
        acc += p.x * wcol[4 * q] + p.y * wcol[4 * q + 1] +
               p.z * wcol[4 * q + 2] + p.w * wcol[4 * q + 3];
      }
      s_lg[n * 20 + b_] = acc;
    }
  }
  __syncthreads();

  if (tid < 144) {
    int kk = tid >> 4, B = tid & 15;
    float s = 0.f, s2 = 0.f;
    for (int a = 0; a < 32; ++a) {
      float v = s_lg[(kk * 32 + a) * 20 + B];
      s += v; s2 += v * v;
    }
    float mu = s * (1.f / 32.f);
    float var = s2 * (1.f / 32.f) - mu * mu;
    s_mu[tid] = mu;
    s_rs[tid] = rsqrtf(var + 1e-5f);
  } else if (tid < 160) {
    int t2 = tid - 144;
    float p = 0.f;
    for (int i = 0; i < 18; ++i) p += s_au[t2 * 18 + i];
    s_pau[t2] = p;
  }
  __syncthreads();

  // gate (writes s_l2 aliasing s_pu)
  {
    float mu9[9], rs9[9];
#pragma unroll
    for (int i2 = 0; i2 < 9; ++i2) {
      mu9[i2] = s_mu[i2 * 16 + b_];
      rs9[i2] = s_rs[i2 * 16 + b_];
    }
#pragma unroll
    for (int half = 0; half < 2; ++half) {
      int a = (tid >> 4) + 16 * half;
      float ga = s_ga[a], be = s_be[a];
      float gn[9], lg9[9];
#pragma unroll
      for (int i2 = 0; i2 < 9; ++i2) {
        float v = s_lg[(i2 * 32 + a) * 20 + b_];
        lg9[i2] = v;
        gn[i2] = (v - mu9[i2]) * rs9[i2] * ga + be;
      }
#pragma unroll
      for (int oo = 0; oo < 9; ++oo) {
        float acc = sp_b[oo];
#pragma unroll
        for (int i2 = 0; i2 < 9; ++i2) acc += sp_w[oo * 9 + i2] * gn[i2];
        s_l2[(oo * 32 + a) * 20 + b_] = 2.f * lg9[oo] + gelu_f(acc);
      }
    }
  }
  __syncthreads();

  // softmax over B per n
  for (int n = tid; n < 288; n += 256) {
    float v[16];
#pragma unroll
    for (int q = 0; q < 4; ++q) {
      float4 t = ld4(&s_l2[n * 20 + 4 * q]);
      v[4 * q] = t.x; v[4 * q + 1] = t.y; v[4 * q + 2] = t.z; v[4 * q + 3] = t.w;
    }
    float m = v[0];
#pragma unroll
    for (int e = 1; e < 16; ++e) m = fmaxf(m, v[e]);
    float s = 0.f;
#pragma unroll
    for (int e = 0; e < 16; ++e) { v[e] = __expf(v[e] - m); s += v[e]; }
    float inv = 1.f / s;
#pragma unroll
    for (int q = 0; q < 4; ++q)
      st4(&s_l2[n * 20 + 4 * q],
          make_float4(v[4 * q] * inv, v[4 * q + 1] * inv, v[4 * q + 2] * inv,
                      v[4 * q + 3] * inv));
  }
  __syncthreads();

  {
    int sl = tid >> 4;
    float part = 0.f;
#pragma unroll 3
    for (int i = 0; i < 18; ++i) {
      int n = sl * 18 + i;
      part += s_au[n] * s_l2[n * 20 + b_];
    }
    s_part[tid] = part;
  }
  __syncthreads();

  if (tid < 16) {
    float s = 0.f;
#pragma unroll
    for (int q = 0; q < 16; ++q) s += s_part[tid + 16 * q];
    s_as[tid] = s;
    float aus = 0.f;
#pragma unroll
    for (int q = 0; q < 16; ++q) aus += s_pau[q];
    out_a[(b * 16 + tid) * 196 + loc] = s / aus;
  }
  __syncthreads();

  {
    float inv_as = 1.f / s_as[(tid >> 3) & 15];
    for (int e = tid; e < 4608; e += 256) {
      int jj = e & 7, B = (e >> 3) & 15, g2 = (e >> 7) & 3, kk = e >> 9;
      int n = kk * 32 + g2 * 8 + jj;
      float v = s_au[n] * s_l2[n * 20 + B] * inv_as;
      ws_cb[row * 4608 + e] = f2bf(v);
    }
  }
#undef s_l2
}

// ---------------------------------------------------------------------------
// Kernel 2: 4 ROWS PER WAVE (H stream amortized 2x per row). grid 896 =
// 8 xcd x 7 x 16 d; block = 4 waves same d; block covers 16 rows (one
// sixteen-group, XCD-aligned with producer). Coeff via volatile loads
// (AGPR-resident per R18); launch_bounds (256,2) for the ~250-reg live set.
// ---------------------------------------------------------------------------
__global__ __launch_bounds__(256, 2) void k_gterm(
    const unsigned short* __restrict__ ws_H,
    const unsigned short* __restrict__ ws_pu,
    const unsigned short* __restrict__ ws_cb,
    const float* __restrict__ mpose_w, const float* __restrict__ mpose_b,
    float* __restrict__ out_po) {
  int bid = blockIdx.x;
  int xcd = bid & 7, q = bid >> 3;        // q in [0,112)
  int k7 = q % 7, d = q / 7;              // d in [0,16)
  int rg = xcd + 8 * k7;                  // sixteen-group in [0,56)
  if (rg >= 49) return;

  int tid = threadIdx.x;
  int w = tid >> 6, l = tid & 63;
  int row0 = rg * 16 + w * 4;             // 4 consecutive rows per wave
  int b_ = l & 15, g = l >> 4;

  const bf16x8 z8 = {0, 0, 0, 0, 0, 0, 0, 0};
  const f32x4 zf = {0.f, 0.f, 0.f, 0.f};

  bf16x8 bmw = z8;
  if (g < 2) {
    const float* mp = mpose_w + (b_ * 16 + d) * 16 + g * 8;
#pragma unroll
    for (int jj = 0; jj < 8; ++jj) bmw[jj] = (short)f2bf(mp[jj]);
  }
  float mb = mpose_b[b_ * 16 + d];
  f32x4 mbv = {mb, mb, mb, mb};

  // coeff frags for 4 rows, volatile-loaded (AGPR-resident, no remat)
  union CU { uint4 u; bf16x8 v; };
  CU c[4][9];
  {
#pragma unroll
    for (int i = 0; i < 4; ++i) {
      const uint4* gC = (const uint4*)ws_cb + (row0 + i) * 576 + l;
#pragma unroll
      for (int kk = 0; kk < 9; ++kk) {
        asm volatile("global_load_dwordx4 %0, %1, off"
                     : "=&v"(c[i][kk].u) : "v"(gC + kk * 64));
      }
    }
    asm volatile("s_waitcnt vmcnt(0)" ::: "memory");
    __builtin_amdgcn_sched_barrier(0);
  }
  const bf16x8* aP0 = (const bf16x8*)ws_pu + (row0 + 0) * 576;
  const bf16x8* aP1 = (const bf16x8*)ws_pu + (row0 + 1) * 576;
  const bf16x8* aP2 = (const bf16x8*)ws_pu + (row0 + 2) * 576;
  const bf16x8* aP3 = (const bf16x8*)ws_pu + (row0 + 3) * 576;
  const bf16x8* aH = (const bf16x8*)ws_H + d * 10368;   // 18*9*64 frags

  bf16x8 an0 = z8, an1 = z8, an2 = z8, an3 = z8;
  if (g < 2) {
    an0 = aP0[l]; an1 = aP1[l]; an2 = aP2[l]; an3 = aP3[l];
  }

  float po0 = 0.f, po1 = 0.f, po2 = 0.f, po3 = 0.f;
  for (int mt = 0; mt < 18; ++mt) {
    bf16x8 h[9];
#pragma unroll
    for (int kk = 0; kk < 9; ++kk) h[kk] = aH[(mt * 9 + kk) * 64 + l];
    bf16x8 a0 = an0, a1 = an1, a2 = an2, a3 = an3;
    if (mt < 17 && g < 2) {
      an0 = aP0[(mt + 1) * 32 + l];
      an1 = aP1[(mt + 1) * 32 + l];
      an2 = aP2[(mt + 1) * 32 + l];
      an3 = aP3[(mt + 1) * 32 + l];
    }
    f32x4 xp0 = __builtin_amdgcn_mfma_f32_16x16x32_bf16(a0, bmw, mbv, 0, 0, 0);
    f32x4 xp1 = __builtin_amdgcn_mfma_f32_16x16x32_bf16(a1, bmw, mbv, 0, 0, 0);
    f32x4 xp2 = __builtin_amdgcn_mfma_f32_16x16x32_bf16(a2, bmw, mbv, 0, 0, 0);
    f32x4 xp3 = __builtin_amdgcn_mfma_f32_16x16x32_bf16(a3, bmw, mbv, 0, 0, 0);
    f32x4 g0 = zf, g1 = zf, g2 = zf, g3 = zf;
#pragma unroll
    for (int kk = 0; kk < 9; ++kk) {
      g0 = __builtin_amdgcn_mfma_f32_16x16x32_bf16(h[kk], c[0][kk].v, g0, 0, 0, 0);
      g1 = __builtin_amdgcn_mfma_f32_16x16x32_bf16(h[kk], c[1][kk].v, g1, 0, 0, 0);
      g2 = __builtin_amdgcn_mfma_f32_16x16x32_bf16(h[kk], c[2][kk].v, g2, 0, 0, 0);
      g3 = __builtin_amdgcn_mfma_f32_16x16x32_bf16(h[kk], c[3][kk].v, g3, 0, 0, 0);
    }
#pragma unroll
    for (int r = 0; r < 4; ++r) {
      po0 += g0[r] * gelu_f(xp0[r]);
      po1 += g1[r] * gelu_f(xp1[r]);
      po2 += g2[r] * gelu_f(xp2[r]);
      po3 += g3[r] * gelu_f(xp3[r]);
    }
  }

  po0 += __shfl_xor(po0, 16); po0 += __shfl_xor(po0, 32);
  po1 += __shfl_xor(po1, 16); po1 += __shfl_xor(po1, 32);
  po2 += __shfl_xor(po2, 16); po2 += __shfl_xor(po2, 32);
  po3 += __shfl_xor(po3, 16); po3 += __shfl_xor(po3, 32);
  if (l < 16) {
    int bb = row0 / 196;
#pragma unroll
    for (int i = 0; i < 4; ++i) {
      int r = row0 + i;
      float v = (i == 0) ? po0 : (i == 1) ? po1 : (i == 2) ? po2 : po3;
      out_po[(((r / 196) * 256) + l * 16 + d) * 196 + (r % 196)] = v;
    }
    (void)bb;
  }
}

// ---------------------------------------------------------------------------
extern "C" void kernel_launch(void* const* d_in, const int* in_sizes, int n_in,
                              void* d_out, int out_size, void* d_ws, size_t ws_size,
                              hipStream_t stream) {
  const float* a_img    = (const float*)d_in[0];
  const float* pose     = (const float*)d_in[1];
  const float* mpose_w  = (const float*)d_in[2];
  const float* mpose_b  = (const float*)d_in[3];
  const float* cpose2_w = (const float*)d_in[4];
  const float* cpose2_b = (const float*)d_in[5];
  const float* cw       = (const float*)d_in[6];
  const float* ln_g     = (const float*)d_in[7];
  const float* ln_b     = (const float*)d_in[8];
  const float* sp_w     = (const float*)d_in[9];
  const float* sp_b     = (const float*)d_in[10];

  float* out = (float*)d_out;
  float* poseT  = (float*)d_ws;                      // 4*196*512
  float* aT     = poseT + 4 * 196 * 512;             // 4*196*32
  unsigned short* ws_H  = (unsigned short*)(aT + 4 * 196 * 32);  // 16*82944
  unsigned short* ws_pu = ws_H + 16 * 82944;         // 784*4608
  unsigned short* ws_cb = ws_pu + 784 * 4608;        // 784*4608

  hipLaunchKernelGGL(k_tr, dim3(4, 17), dim3(256), 0, stream,
                     pose, a_img, poseT, aT);
  hipLaunchKernelGGL(k_rowprep, dim3(992), dim3(256), 0, stream,
                     cw, poseT, aT, cpose2_w, cpose2_b, ln_g, ln_b, sp_w, sp_b,
                     out, ws_pu, ws_cb, ws_H);
  hipLaunchKernelGGL(k_gterm, dim3(896), dim3(256), 0, stream,
                     ws_H, ws_pu, ws_cb, mpose_w, mpose_b, out + 12544);
}

// Round 20
// 94.257 us; speedup vs baseline: 1.0608x; 1.0608x over previous
//
#include <hip/hip_runtime.h>
#include <math.h>

// A=32, B=16, C=16, D=16, KK=9, KKA=288, BSZ=4, L=196, BL=784
// po[b_,d] = sum_t G'_d[t,b_] * x[t,b_,d],  G'_d = (H_d + I) @ coeff
//   H_d[t,n] = h_d[(n-t) mod 288] (row-invariant circulant)
//   x = gelu(pu @ mpose_w_d^T + mb_d) via MFMA, same C/D layout as G'.

typedef __attribute__((ext_vector_type(8))) short bf16x8;
typedef __attribute__((ext_vector_type(4))) float f32x4;

__device__ inline float4 ld4(const float* p) { return *reinterpret_cast<const float4*>(p); }
__device__ inline void st4(float* p, float4 v) { *reinterpret_cast<float4*>(p) = v; }
__device__ inline unsigned short f2bf(float f) {
  union { float f; unsigned int i; } v; v.f = f;
  unsigned int r = v.i + 0x7FFFu + ((v.i >> 16) & 1u);
  return (unsigned short)(r >> 16);
}
// exact-gelu via A&S 7.1.26 erf approx, |err_erf| < 1.5e-7
__device__ inline float gelu_f(float v) {
  float u = v * 0.70710678118654752f;
  float au = fabsf(u);
  float t = __builtin_amdgcn_rcpf(fmaf(0.3275911f, au, 1.f));
  float poly = t * fmaf(t, fmaf(t, fmaf(t, fmaf(t, 1.061405429f, -1.453152027f),
                                        1.421413741f), -0.284496736f),
                        0.254829592f);
  float e = __expf(-u * u);
  float r = fmaf(-poly, e, 1.f);
  float erfv = copysignf(r, u);
  return 0.5f * v * (1.f + erfv);
}

// ---------------------------------------------------------------------------
// Kernel TR: NHWC transpose only. grid(4,17): pose -> poseT, ch=16 -> aT.
// ---------------------------------------------------------------------------
__global__ __launch_bounds__(256) void k_tr(const float* __restrict__ pose,
                                            const float* __restrict__ a_img,
                                            float* __restrict__ poseT,
                                            float* __restrict__ aT) {
  __shared__ float s[32 * 201];
  int b = blockIdx.x, ch = blockIdx.y, tid = threadIdx.x;
  const float* src = (ch < 16) ? (pose + (b * 512 + ch * 32) * 196)
                               : (a_img + b * 32 * 196);
  for (int e = tid; e < 6272; e += 256) {
    int c = e / 196, l = e - c * 196;
    s[c * 201 + l] = src[e];
  }
  __syncthreads();
  if (ch < 16) {
    float* dst = poseT + b * 196 * 512 + ch * 32;
    for (int e = tid; e < 6272; e += 256) {
      int l = e >> 5, c = e & 31;
      dst[l * 512 + c] = s[c * 201 + l];
    }
  } else {
    float* dst = aT + b * 196 * 32;
    for (int e = tid; e < 6272; e += 256) {
      int l = e >> 5, c = e & 31;
      dst[l * 32 + c] = s[c * 201 + l];
    }
  }
}

// ---------------------------------------------------------------------------
// Kernel 1 (merged): bids 0..95 = htab (d=bid/6, chunk=bid%6), LDS aliased
// into s_pu; bids 96..927 = rowprep with XCD-aligned decode.
// ws_H: [d][mt 18][kk 9][lane 64][j 8]; t=mt*16+(l&15), n=kk*32+(l>>4)*8+j.
// ---------------------------------------------------------------------------
__global__ __launch_bounds__(256) void k_rowprep(
    const float* __restrict__ cw,
    const float* __restrict__ poseT, const float* __restrict__ aT,
    const float* __restrict__ cpose2_w, const float* __restrict__ cpose2_b,
    const float* __restrict__ ln_g, const float* __restrict__ ln_b,
    const float* __restrict__ sp_w, const float* __restrict__ sp_b,
    float* __restrict__ out_a, unsigned short* __restrict__ ws_pu,
    unsigned short* __restrict__ ws_cb, unsigned short* __restrict__ ws_H) {
  __shared__ __align__(16) float s_pu[288 * 20];   // aliased: s_l2 / htab tables
#define s_l2 s_pu
  __shared__ __align__(16) float s_lg[288 * 20];
  __shared__ float s_au[288];
  __shared__ float s_mu[144], s_rs[144];
  __shared__ float s_ga[32], s_be[32];
  __shared__ float s_part[256], s_pau[16];
  __shared__ float s_as[16];

  int bid = blockIdx.x, tid = threadIdx.x;

  if (bid < 96) {
    // ---- htab branch (LDS overlaid on s_pu) ----
    float* s_h2 = s_pu;             // 576
    float* s_cs = s_pu + 576;       // 288
    float* s_sn = s_pu + 864;       // 288
    float* s_wr = s_pu + 1152;      // 145
    float* s_wi = s_pu + 1297;      // 145
    int d = bid / 6, chunk = bid % 6;
    for (int m = tid; m < 288; m += 256) {
      float sn, cs;
      sincosf((float)m * (6.283185307179586f / 288.f), &sn, &cs);
      s_cs[m] = cs; s_sn[m] = sn;
    }
    for (int f = tid; f < 145; f += 256) {
      s_wr[f] = cw[(f * 16 + d) * 2 + 0];
      s_wi[f] = cw[(f * 16 + d) * 2 + 1];
    }
    __syncthreads();
    for (int t = tid; t < 288; t += 256) {
      float acc = s_wr[0] + ((t & 1) ? -s_wr[144] : s_wr[144]);
      for (int f = 1; f < 144; ++f) {
        int m = (f * t) % 288;
        acc = fmaf(2.f * s_wr[f], s_cs[m], acc);
        acc = fmaf(-2.f * s_wi[f], s_sn[m], acc);
      }
      float h = acc * (1.f / 288.f);
      s_h2[t] = h;
      s_h2[t + 288] = h;
    }
    __syncthreads();
    for (int e = tid; e < 13824; e += 256) {
      int j = e & 7, l = (e >> 3) & 63;
      int kk = (e >> 9) % 9, mtl = (e >> 9) / 9;
      int mt = chunk * 3 + mtl;
      int m = l & 15, g = l >> 4;
      int n = kk * 32 + g * 8 + j, t = mt * 16 + m;
      float v = s_h2[n - t + 288] + ((n == t) ? 1.f : 0.f);
      ws_H[d * 82944 + ((mt * 9 + kk) * 64 + l) * 8 + j] = f2bf(v);
    }
    return;
  }

  // ---- rowprep branch ----
  int rb = bid - 96;
  int x = rb & 7, j = rb >> 3;
  int o = x + 8 * (j % 13);
  if (o >= 98) return;
  int row = o * 8 + (j / 13);

  int b = row / 196, loc = row % 196, i0 = loc / 14, j0 = loc % 14;
  int b_ = tid & 15;

  if (tid < 32) { s_ga[tid] = ln_g[tid]; s_be[tid] = ln_b[tid]; }

  float wcol[16];
#pragma unroll
  for (int q = 0; q < 4; ++q) {
    float4 v = ld4(&cpose2_w[b_ * 16 + 4 * q]);
    wcol[4 * q] = v.x; wcol[4 * q + 1] = v.y;
    wcol[4 * q + 2] = v.z; wcol[4 * q + 3] = v.w;
  }
  float cbv = cpose2_b[b_];

  const float* pT = poseT + b * 196 * 512;
  for (int e = tid; e < 1152; e += 256) {
    int q = e & 3, n = e >> 2;
    int kk = n >> 5, a = n & 31;
    int ki = (kk * 11) >> 5, kj = kk - 3 * ki;
    int yy = i0 + ki - 1, xx = j0 + kj - 1;
    float4 v = make_float4(0.f, 0.f, 0.f, 0.f);
    if ((unsigned)yy < 14u && (unsigned)xx < 14u)
      v = ld4(&pT[(yy * 14 + xx) * 512 + a * 16 + q * 4]);
    st4(&s_pu[n * 20 + q * 4], v);
  }
  const float* aTb = aT + b * 196 * 32;
  for (int n = tid; n < 288; n += 256) {
    int kk = n >> 5, a = n & 31;
    int ki = (kk * 11) >> 5, kj = kk - 3 * ki;
    int yy = i0 + ki - 1, xx = j0 + kj - 1;
    float v = 0.f;
    if ((unsigned)yy < 14u && (unsigned)xx < 14u)
      v = aTb[(yy * 14 + xx) * 32 + a];
    s_au[n] = v;
  }
  __syncthreads();

  // pu compact A-frags (EARLY — s_pu dead after logit pass)
  for (int e = tid; e < 4608; e += 256) {
    int jj = e & 7, l2 = (e >> 3) & 31, mt = e >> 8;
    int m = l2 & 15, c = (l2 >> 4) * 8 + jj;
    ws_pu[row * 4608 + e] = f2bf(s_pu[(mt * 16 + m) * 20 + c]);
  }

  // logit[n,b_]
  {
    int n0 = tid >> 4;
#pragma unroll 3
    for (int k = 0; k < 18; ++k) {
      int n = n0 + 16 * k;
      const float* pr = &s_pu[n * 20];
      float acc = cbv;
#pragma unroll
      for (int q = 0; q < 4; ++q) {
        float4 p = ld4(pr + 4 * q);
        acc += p.x * wcol[4 * q] + p.y * wcol[4 * q + 1] +
               p.z * wcol[4 * q + 2] + p.w * wcol[4 * q + 3];
      }
      s_lg[n * 20 + b_] = acc;
    }
  }
  __syncthreads();

  if (tid < 144) {
    int kk = tid >> 4, B = tid & 15;
    float s = 0.f, s2 = 0.f;
    for (int a = 0; a < 32; ++a) {
      float v = s_lg[(kk * 32 + a) * 20 + B];
      s += v; s2 += v * v;
    }
    float mu = s * (1.f / 32.f);
    float var = s2 * (1.f / 32.f) - mu * mu;
    s_mu[tid] = mu;
    s_rs[tid] = rsqrtf(var + 1e-5f);
  } else if (tid < 160) {
    int t2 = tid - 144;
    float p = 0.f;
    for (int i = 0; i < 18; ++i) p += s_au[t2 * 18 + i];
    s_pau[t2] = p;
  }
  __syncthreads();

  // gate (writes s_l2 aliasing s_pu)
  {
    float mu9[9], rs9[9];
#pragma unroll
    for (int i2 = 0; i2 < 9; ++i2) {
      mu9[i2] = s_mu[i2 * 16 + b_];
      rs9[i2] = s_rs[i2 * 16 + b_];
    }
#pragma unroll
    for (int half = 0; half < 2; ++half) {
      int a = (tid >> 4) + 16 * half;
      float ga = s_ga[a], be = s_be[a];
      float gn[9], lg9[9];
#pragma unroll
      for (int i2 = 0; i2 < 9; ++i2) {
        float v = s_lg[(i2 * 32 + a) * 20 + b_];
        lg9[i2] = v;
        gn[i2] = (v - mu9[i2]) * rs9[i2] * ga + be;
      }
#pragma unroll
      for (int oo = 0; oo < 9; ++oo) {
        float acc = sp_b[oo];
#pragma unroll
        for (int i2 = 0; i2 < 9; ++i2) acc += sp_w[oo * 9 + i2] * gn[i2];
        s_l2[(oo * 32 + a) * 20 + b_] = 2.f * lg9[oo] + gelu_f(acc);
      }
    }
  }
  __syncthreads();

  // softmax over B per n
  for (int n = tid; n < 288; n += 256) {
    float v[16];
#pragma unroll
    for (int q = 0; q < 4; ++q) {
      float4 t = ld4(&s_l2[n * 20 + 4 * q]);
      v[4 * q] = t.x; v[4 * q + 1] = t.y; v[4 * q + 2] = t.z; v[4 * q + 3] = t.w;
    }
    float m = v[0];
#pragma unroll
    for (int e = 1; e < 16; ++e) m = fmaxf(m, v[e]);
    float s = 0.f;
#pragma unroll
    for (int e = 0; e < 16; ++e) { v[e] = __expf(v[e] - m); s += v[e]; }
    float inv = 1.f / s;
#pragma unroll
    for (int q = 0; q < 4; ++q)
      st4(&s_l2[n * 20 + 4 * q],
          make_float4(v[4 * q] * inv, v[4 * q + 1] * inv, v[4 * q + 2] * inv,
                      v[4 * q + 3] * inv));
  }
  __syncthreads();

  {
    int sl = tid >> 4;
    float part = 0.f;
#pragma unroll 3
    for (int i = 0; i < 18; ++i) {
      int n = sl * 18 + i;
      part += s_au[n] * s_l2[n * 20 + b_];
    }
    s_part[tid] = part;
  }
  __syncthreads();

  if (tid < 16) {
    float s = 0.f;
#pragma unroll
    for (int q = 0; q < 16; ++q) s += s_part[tid + 16 * q];
    s_as[tid] = s;
    float aus = 0.f;
#pragma unroll
    for (int q = 0; q < 16; ++q) aus += s_pau[q];
    out_a[(b * 16 + tid) * 196 + loc] = s / aus;
  }
  __syncthreads();

  {
    float inv_as = 1.f / s_as[(tid >> 3) & 15];
    for (int e = tid; e < 4608; e += 256) {
      int jj = e & 7, B = (e >> 3) & 15, g2 = (e >> 7) & 3, kk = e >> 9;
      int n = kk * 32 + g2 * 8 + jj;
      float v = s_au[n] * s_l2[n * 20 + B] * inv_as;
      ws_cb[row * 4608 + e] = f2bf(v);
    }
  }
#undef s_l2
}

// ---------------------------------------------------------------------------
// Kernel 2: R18-exact best body (2 rows/wave). Coeff via volatile loads
// (unified-file resident); launch_bounds (256,2).
// grid 1664 = 8 xcd x 13 x 16 d; block = 4 waves same d; wave = 2 rows.
// ---------------------------------------------------------------------------
__global__ __launch_bounds__(256, 2) void k_gterm(
    const unsigned short* __restrict__ ws_H,
    const unsigned short* __restrict__ ws_pu,
    const unsigned short* __restrict__ ws_cb,
    const float* __restrict__ mpose_w, const float* __restrict__ mpose_b,
    float* __restrict__ out_po) {
  int bid = blockIdx.x;
  int xcd = bid & 7, q = bid >> 3;        // q in [0,208)
  int k13 = q % 13, d = q / 13;           // d in [0,16)
  int ro = xcd + 8 * k13;                 // row-octet in [0,104)
  if (ro >= 98) return;

  int tid = threadIdx.x;
  int w = tid >> 6, l = tid & 63;
  int row0 = ro * 8 + w * 2, row1 = row0 + 1;
  int b_ = l & 15, g = l >> 4;

  const bf16x8 z8 = {0, 0, 0, 0, 0, 0, 0, 0};
  const f32x4 zf = {0.f, 0.f, 0.f, 0.f};

  bf16x8 bmw = z8;
  if (g < 2) {
    const float* mp = mpose_w + (b_ * 16 + d) * 16 + g * 8;
#pragma unroll
    for (int jj = 0; jj < 8; ++jj) bmw[jj] = (short)f2bf(mp[jj]);
  }
  float mb = mpose_b[b_ * 16 + d];
  f32x4 mbv = {mb, mb, mb, mb};

  // coeff frags loaded via volatile asm: non-rematerializable, stay resident.
  union CU { uint4 u; bf16x8 v; };
  CU c0[9], c1[9];
  {
    const uint4* gC0 = (const uint4*)ws_cb + row0 * 576 + l;
    const uint4* gC1 = (const uint4*)ws_cb + row1 * 576 + l;
#pragma unroll
    for (int kk = 0; kk < 9; ++kk) {
      asm volatile("global_load_dwordx4 %0, %1, off"
                   : "=&v"(c0[kk].u) : "v"(gC0 + kk * 64));
      asm volatile("global_load_dwordx4 %0, %1, off"
                   : "=&v"(c1[kk].u) : "v"(gC1 + kk * 64));
    }
    asm volatile("s_waitcnt vmcnt(0)" ::: "memory");
    __builtin_amdgcn_sched_barrier(0);
  }
  const bf16x8* aP0 = (const bf16x8*)ws_pu + row0 * 576;
  const bf16x8* aP1 = (const bf16x8*)ws_pu + row1 * 576;
  const bf16x8* aH = (const bf16x8*)ws_H + d * 10368;   // 18*9*64 frags

  bf16x8 an0 = z8, an1 = z8;
  if (g < 2) { an0 = aP0[l]; an1 = aP1[l]; }

  float po0 = 0.f, po1 = 0.f;
  for (int mt = 0; mt < 18; ++mt) {
    bf16x8 h[9];
#pragma unroll
    for (int kk = 0; kk < 9; ++kk) h[kk] = aH[(mt * 9 + kk) * 64 + l];
    bf16x8 a0 = an0, a1 = an1;
    if (mt < 17 && g < 2) {
      an0 = aP0[(mt + 1) * 32 + l];
      an1 = aP1[(mt + 1) * 32 + l];
    }
    f32x4 xp0 = __builtin_amdgcn_mfma_f32_16x16x32_bf16(a0, bmw, mbv, 0, 0, 0);
    f32x4 xp1 = __builtin_amdgcn_mfma_f32_16x16x32_bf16(a1, bmw, mbv, 0, 0, 0);
    f32x4 g0 = zf, g1 = zf;
#pragma unroll
    for (int kk = 0; kk < 9; ++kk) {
      g0 = __builtin_amdgcn_mfma_f32_16x16x32_bf16(h[kk], c0[kk].v, g0, 0, 0, 0);
      g1 = __builtin_amdgcn_mfma_f32_16x16x32_bf16(h[kk], c1[kk].v, g1, 0, 0, 0);
    }
#pragma unroll
    for (int r = 0; r < 4; ++r) {
      po0 += g0[r] * gelu_f(xp0[r]);
      po1 += g1[r] * gelu_f(xp1[r]);
    }
  }

  po0 += __shfl_xor(po0, 16);
  po0 += __shfl_xor(po0, 32);
  po1 += __shfl_xor(po1, 16);
  po1 += __shfl_xor(po1, 32);
  if (l < 16) {
    int bb = row0 / 196, lc0 = row0 % 196, lc1 = row1 % 196;
    out_po[((bb * 256) + l * 16 + d) * 196 + lc0] = po0;
    out_po[((bb * 256) + l * 16 + d) * 196 + lc1] = po1;
  }
}

// ---------------------------------------------------------------------------
extern "C" void kernel_launch(void* const* d_in, const int* in_sizes, int n_in,
                              void* d_out, int out_size, void* d_ws, size_t ws_size,
                              hipStream_t stream) {
  const float* a_img    = (const float*)d_in[0];
  const float* pose     = (const float*)d_in[1];
  const float* mpose_w  = (const float*)d_in[2];
  const float* mpose_b  = (const float*)d_in[3];
  const float* cpose2_w = (const float*)d_in[4];
  const float* cpose2_b = (const float*)d_in[5];
  const float* cw       = (const float*)d_in[6];
  const float* ln_g     = (const float*)d_in[7];
  const float* ln_b     = (const float*)d_in[8];
  const float* sp_w     = (const float*)d_in[9];
  const float* sp_b     = (const float*)d_in[10];

  float* out = (float*)d_out;
  float* poseT  = (float*)d_ws;                      // 4*196*512
  float* aT     = poseT + 4 * 196 * 512;             // 4*196*32
  unsigned short* ws_H  = (unsigned short*)(aT + 4 * 196 * 32);  // 16*82944
  unsigned short* ws_pu = ws_H + 16 * 82944;         // 784*4608
  unsigned short* ws_cb = ws_pu + 784 * 4608;        // 784*4608

  hipLaunchKernelGGL(k_tr, dim3(4, 17), dim3(256), 0, stream,
                     pose, a_img, poseT, aT);
  hipLaunchKernelGGL(k_rowprep, dim3(928), dim3(256), 0, stream,
                     cw, poseT, aT, cpose2_w, cpose2_b, ln_g, ln_b, sp_w, sp_b,
                     out, ws_pu, ws_cb, ws_H);
  hipLaunchKernelGGL(k_gterm, dim3(1664), dim3(256), 0, stream,
                     ws_H, ws_pu, ws_cb, mpose_w, mpose_b, out + 12544);
}